// Round 1
// baseline (14797.963 us; speedup 1.0000x reference)
//
#include <hip/hip_runtime.h>
#include <cstdint>
#include <cmath>

// Problem constants
#define B_    8
#define H_    72
#define W_    72
#define C_    16
#define C3_   48
#define HP_   16
#define HE_   128
#define T_    64
#define NCELL 41472      // B*H*W

#define IBLK  648        // NCELL*4/256 interior blocks (thread = cell,quad)
#define NEDGE 2272       // (2*72 + 2*70) * 8 boundary cells
#define EBLK  36         // ceil(NEDGE*4/256)
#define S0STR 49         // LDS row stride for fc0 (f64), bank-conflict-free for 4-lane e-split

// ---------------------------------------------------------------------------
// JAX threefry2x32 (20 rounds)
// ---------------------------------------------------------------------------
__host__ __device__ __forceinline__ void threefry2x32(uint32_t k0, uint32_t k1,
                                                      uint32_t& x0, uint32_t& x1) {
  uint32_t ks2 = k0 ^ k1 ^ 0x1BD11BDAu;
  x0 += k0; x1 += k1;
#define TF_R(r) { x0 += x1; x1 = (x1 << (r)) | (x1 >> (32 - (r))); x1 ^= x0; }
  TF_R(13) TF_R(15) TF_R(26) TF_R(6)
  x0 += k1; x1 += ks2 + 1u;
  TF_R(17) TF_R(29) TF_R(16) TF_R(24)
  x0 += ks2; x1 += k0 + 2u;
  TF_R(13) TF_R(15) TF_R(26) TF_R(6)
  x0 += k0; x1 += k1 + 3u;
  TF_R(17) TF_R(29) TF_R(16) TF_R(24)
  x0 += k1; x1 += ks2 + 4u;
  TF_R(13) TF_R(15) TF_R(26) TF_R(6)
  x0 += ks2; x1 += k0 + 5u;
#undef TF_R
}

// ---------------------------------------------------------------------------
// init: f32 input -> f64 state; un = 1
// ---------------------------------------------------------------------------
__global__ void k_init(const float* __restrict__ xin, double* __restrict__ xA,
                       double* __restrict__ un) {
  int idx = blockIdx.x * 256 + threadIdx.x;
  if (idx < NCELL * C_) xA[idx] = (double)xin[idx];
  if (idx < NCELL) un[idx] = 1.0;
}

// ---------------------------------------------------------------------------
// prep (once): effective 5x5 conv1 weights (conv1 o perceive, exact f64
// combination: sobel coeffs are powers of two -> products exact, sums ~1e-16),
// plus f64 copies of fc0 (transposed, stride-49 padded), fc1, w2, biases.
// ---------------------------------------------------------------------------
__global__ void k_prep(const float* __restrict__ w1, const float* __restrict__ b1,
                       const float* __restrict__ f0w, const float* __restrict__ f0b,
                       const float* __restrict__ f1w, const float* __restrict__ w2,
                       double* __restrict__ weffd, double* __restrict__ b1d,
                       double* __restrict__ fc0t, double* __restrict__ fc1d,
                       double* __restrict__ w2d, double* __restrict__ f0bd) {
  int gid = blockIdx.x * 256 + threadIdx.x;
  const int stride = 26 * 256;
  // w_eff[u][v][c][oc] = sum_g sum_{ei+di=u, ej+dj=v} w1[ei][ej][g*16+c][oc]*K_g[di][dj]
  for (int t = gid; t < 6400; t += stride) {
    int oc = t & 15;
    int c  = (t >> 4) & 15;
    int pos = t >> 8;             // 0..24
    int u = pos / 5, v = pos % 5;
    double acc = 0.0;
    for (int ei = 0; ei < 3; ei++) {
      int di = u - ei; if (di < 0 || di > 2) continue;
      for (int ej = 0; ej < 3; ej++) {
        int dj = v - ej; if (dj < 0 || dj > 2) continue;
        const float* wb = w1 + (size_t)((ei * 3 + ej) * C3_) * HP_ + oc;
        // g=0: identity at (1,1)
        if (di == 1 && dj == 1) acc += (double)wb[c * HP_];
        // K1 (dw1): rows {-1,0,+1}*0.125, col weight {1,2,1}
        double rf1 = (di == 0) ? -0.125 : (di == 2) ? 0.125 : 0.0;
        if (rf1 != 0.0) {
          double cf1 = (dj == 1) ? 2.0 : 1.0;
          acc += (double)wb[(C_ + c) * HP_] * (rf1 * cf1);
        }
        // K2 (dw2): cols {-1,0,+1}*0.125, row weight {1,2,1}
        double cf2 = (dj == 0) ? -0.125 : (dj == 2) ? 0.125 : 0.0;
        if (cf2 != 0.0) {
          double rf2 = (di == 1) ? 2.0 : 1.0;
          acc += (double)wb[(2 * C_ + c) * HP_] * (cf2 * rf2);
        }
      }
    }
    weffd[t] = acc;
  }
  // fc0 transposed: fc0t[e*49 + k] = f0w[k*128 + e]   (exact f32->f64)
  for (int t = gid; t < C3_ * HE_; t += stride) {
    int k = t >> 7, e = t & 127;
    fc0t[e * S0STR + k] = (double)f0w[k * HE_ + e];
  }
  for (int t = gid; t < HE_ * C_; t += stride) fc1d[t] = (double)f1w[t];
  for (int t = gid; t < 144; t += stride) w2d[t] = (double)w2[t];
  for (int t = gid; t < HE_; t += stride) f0bd[t] = (double)f0b[t];
  for (int t = gid; t < HP_; t += stride) b1d[t] = (double)b1[t];
}

// ---------------------------------------------------------------------------
// conv1 fused with perceive: hbuf = relu(conv5x5(x, w_eff) + b1).
// Interior cells (i,j in [1,70]): direct 5x5 (zero-pad x == reference).
// Boundary ring: reference zero-pads PERC, not x -> exact two-stage fallback,
// handled by EBLK extra blocks (interior waves never run the slow path).
// thread = (cell, oc-quad)
// ---------------------------------------------------------------------------
__global__ void __launch_bounds__(256) k_conv1f(const double* __restrict__ x,
    const double* __restrict__ weffd, const double* __restrict__ b1d,
    const float* __restrict__ w1f, double* __restrict__ hbuf) {
  __shared__ double sw[6400];   // [pos][ic][oc] 51.2 KB
  __shared__ double sb[HP_];
  for (int t = threadIdx.x; t < 6400; t += 256) sw[t] = weffd[t];
  if (threadIdx.x < HP_) sb[threadIdx.x] = b1d[threadIdx.x];
  __syncthreads();

  if (blockIdx.x < IBLK) {
    int idx = blockIdx.x * 256 + threadIdx.x;
    int q = idx & 3;
    int cell = idx >> 2;
    int j = cell % W_; int t2 = cell / W_; int i = t2 % H_; int b = t2 / H_;
    if (i == 0 || i == H_ - 1 || j == 0 || j == W_ - 1) return;  // edge blocks own these
    double acc0 = sb[(q << 2) + 0], acc1 = sb[(q << 2) + 1];
    double acc2 = sb[(q << 2) + 2], acc3 = sb[(q << 2) + 3];
    for (int u = 0; u < 5; u++) {
      int ii = i + u - 2; if (ii < 0 || ii >= H_) continue;
      for (int v = 0; v < 5; v++) {
        int jj = j + v - 2; if (jj < 0 || jj >= W_) continue;
        const double* xp = x + ((size_t)((b * H_ + ii) * W_ + jj) << 4);
        const double* wpos = sw + (u * 5 + v) * 256 + (q << 2);
#pragma unroll
        for (int ic = 0; ic < 16; ic += 2) {
          double x0 = xp[ic], x1 = xp[ic + 1];
          const double* w4a = wpos + ic * 16;
          const double* w4b = w4a + 16;
          acc0 = fma(x0, w4a[0], acc0); acc1 = fma(x0, w4a[1], acc1);
          acc2 = fma(x0, w4a[2], acc2); acc3 = fma(x0, w4a[3], acc3);
          acc0 = fma(x1, w4b[0], acc0); acc1 = fma(x1, w4b[1], acc1);
          acc2 = fma(x1, w4b[2], acc2); acc3 = fma(x1, w4b[3], acc3);
        }
      }
    }
    double* hp = hbuf + ((size_t)cell << 4) + (q << 2);
    hp[0] = acc0 > 0.0 ? acc0 : 0.0;
    hp[1] = acc1 > 0.0 ? acc1 : 0.0;
    hp[2] = acc2 > 0.0 ? acc2 : 0.0;
    hp[3] = acc3 > 0.0 ? acc3 : 0.0;
  } else {
    // ---- boundary ring: exact two-stage (perc on the fly, original w1) ----
    int eidx = (blockIdx.x - IBLK) * 256 + threadIdx.x;
    if (eidx >= NEDGE * 4) return;
    int q = eidx & 3;
    int e = eidx >> 2;
    int b = e / 284, r = e % 284;
    int i, j;
    if (r < 72)       { i = 0;       j = r; }
    else if (r < 144) { i = H_ - 1;  j = r - 72; }
    else if (r < 214) { i = r - 143; j = 0; }
    else              { i = r - 213; j = W_ - 1; }
    int cell = (b * H_ + i) * W_ + j;
    double acc0 = sb[(q << 2) + 0], acc1 = sb[(q << 2) + 1];
    double acc2 = sb[(q << 2) + 2], acc3 = sb[(q << 2) + 3];
    for (int ei = 0; ei < 3; ei++) {
      int pi = i + ei - 1; if (pi < 0 || pi >= H_) continue;
      for (int ej = 0; ej < 3; ej++) {
        int pj = j + ej - 1; if (pj < 0 || pj >= W_) continue;
        const float* wb = w1f + (size_t)((ei * 3 + ej) * C3_) * HP_ + (q << 2);
        for (int c = 0; c < C_; c++) {
          double v[3][3];
#pragma unroll
          for (int a2 = 0; a2 < 3; a2++) {
#pragma unroll
            for (int b2i = 0; b2i < 3; b2i++) {
              int ii2 = pi + a2 - 1, jj2 = pj + b2i - 1;
              bool ok = (ii2 >= 0 && ii2 < H_ && jj2 >= 0 && jj2 < W_);
              v[a2][b2i] = ok ? x[(((size_t)((b * H_ + ii2) * W_ + jj2)) << 4) + c] : 0.0;
            }
          }
          double ctr = v[1][1];
          double dw1 = (-v[0][0] - 2.0 * v[0][1] - v[0][2] + v[2][0] + 2.0 * v[2][1] + v[2][2]) * 0.125;
          double dw2 = (-v[0][0] + v[0][2] - 2.0 * v[1][0] + 2.0 * v[1][2] - v[2][0] + v[2][2]) * 0.125;
          const float* w0 = wb + c * HP_;
          const float* wA = wb + (C_ + c) * HP_;
          const float* wB = wb + (2 * C_ + c) * HP_;
          acc0 += ctr * (double)w0[0] + dw1 * (double)wA[0] + dw2 * (double)wB[0];
          acc1 += ctr * (double)w0[1] + dw1 * (double)wA[1] + dw2 * (double)wB[1];
          acc2 += ctr * (double)w0[2] + dw1 * (double)wA[2] + dw2 * (double)wB[2];
          acc3 += ctr * (double)w0[3] + dw1 * (double)wA[3] + dw2 * (double)wB[3];
        }
      }
    }
    double* hp = hbuf + ((size_t)cell << 4) + (q << 2);
    hp[0] = acc0 > 0.0 ? acc0 : 0.0;
    hp[1] = acc1 > 0.0 ? acc1 : 0.0;
    hp[2] = acc2 > 0.0 ? acc2 : 0.0;
    hp[3] = acc3 > 0.0 ? acc3 : 0.0;
  }
}

// ---------------------------------------------------------------------------
// fused conv2 + update: 4 threads per cell (quad).
//  - conv2: ic split by q, quad shfl_xor reduce -> fresh lambda (lamNext)
//  - update: perc recomputed on the fly (bit-identical to k_perceive),
//    MLP 48->128->16 with e = 4m+q split, partial dx reduced over quad,
//    threefry bernoulli with lagged lam (n==0 uses fresh), bookkeeping.
// ---------------------------------------------------------------------------
__global__ void __launch_bounds__(256) k_upd(
    const double* __restrict__ x, const double* __restrict__ hbuf,
    const double* __restrict__ lamPrev, const double* __restrict__ fc0t,
    const double* __restrict__ fc1d, const double* __restrict__ w2d,
    const double* __restrict__ f0bd, const float* __restrict__ b2,
    double* __restrict__ lamNext, double* __restrict__ xn,
    float* __restrict__ out_upd, double* __restrict__ un,
    float* __restrict__ out_lam, double* __restrict__ p_buf,
    uint32_t k0, uint32_t k1, int n) {
  __shared__ double s0[HE_ * S0STR];   // 50.2 KB, stride-49: conflict-free e-split
  __shared__ double sw2[144];
  __shared__ double sb0[HE_];
  for (int t = threadIdx.x; t < HE_ * S0STR; t += 256) {
    int e = t / S0STR, k = t - e * S0STR;
    s0[t] = (k < C3_) ? fc0t[t] : 0.0;
  }
  if (threadIdx.x < 144) sw2[threadIdx.x] = w2d[threadIdx.x];
  if (threadIdx.x < HE_) sb0[threadIdx.x] = f0bd[threadIdx.x];
  __syncthreads();
  int idx = blockIdx.x * 256 + threadIdx.x;
  int q = idx & 3;
  int cell = idx >> 2;
  int j = cell % W_; int t2 = cell / W_; int i = t2 % H_; int b = t2 / H_;

  // ---- conv2 (fresh lambda), ic-subset q ----
  double z = 0.0;
  for (int di = 0; di < 3; di++) {
    int ii = i + di - 1; if (ii < 0 || ii >= H_) continue;
    for (int dj = 0; dj < 3; dj++) {
      int jj = j + dj - 1; if (jj < 0 || jj >= W_) continue;
      const double* hh = hbuf + ((size_t)((b * H_ + ii) * W_ + jj) << 4) + (q << 2);
      const double* ww = sw2 + (di * 3 + dj) * HP_ + (q << 2);
      z = fma(hh[0], ww[0], z); z = fma(hh[1], ww[1], z);
      z = fma(hh[2], ww[2], z); z = fma(hh[3], ww[3], z);
    }
  }
  z += __shfl_xor(z, 1);
  z += __shfl_xor(z, 2);
  z += (double)b2[0];
  double lamF = 1.0 / (1.0 + exp(-z));
  if (q == 0) lamNext[cell] = lamF;
  double l = (n == 0) ? lamF : lamPrev[cell];

  // ---- scan bookkeeping with lagged lam ----
  if (n >= 1 && q == 0) {
    size_t o = (size_t)(n - 1) * NCELL + cell;
    out_lam[o] = (float)l;
    double u = un[cell];
    p_buf[o] = u * l + 1e-6;
    un[cell] = u * (1.0 - l);
  }

  // ---- RNG (identical in all 4 lanes) ----
  uint32_t r0 = 0u, r1 = (uint32_t)cell;
  threefry2x32(k0, k1, r0, r1);
  double uf = (double)(r0 ^ r1) * 0x1p-32;
  double upd = (uf < l) ? 0.0 : 1.0;
  if (q == 0) out_upd[(size_t)n * NCELL + cell] = (float)upd;

  // ---- perceive on the fly (exact p-order => bit-identical to k_perceive) ----
  double pv[C3_];
#pragma unroll
  for (int k = 0; k < C3_; k++) pv[k] = 0.0;
#pragma unroll
  for (int p = 0; p < 9; p++) {
    const int di = p / 3, dj = p % 3;
    // scaled sobel coeffs (powers of two: exact, commutes with the *0.125 form)
    const double k1c = (di == 0 ? -0.125 : di == 2 ? 0.125 : 0.0) * (dj == 1 ? 2.0 : 1.0);
    const double k2c = (dj == 0 ? -0.125 : dj == 2 ? 0.125 : 0.0) * (di == 1 ? 2.0 : 1.0);
    int ii = i + di - 1, jj = j + dj - 1;
    if (ii < 0 || ii >= H_ || jj < 0 || jj >= W_) continue;
    const double* xp = x + ((size_t)((b * H_ + ii) * W_ + jj) << 4);
#pragma unroll
    for (int c = 0; c < C_; c++) {
      double xv = xp[c];
      if (p == 4) pv[c] += xv;
      if (k1c != 0.0) pv[C_ + c] = fma(k1c, xv, pv[C_ + c]);
      if (k2c != 0.0) pv[2 * C_ + c] = fma(k2c, xv, pv[2 * C_ + c]);
    }
  }

  // ---- MLP: e = 4m+q, two chains for ILP ----
  double dx[C_];
#pragma unroll
  for (int c = 0; c < C_; c++) dx[c] = 0.0;
  for (int m = 0; m < 32; m += 2) {
    int e0 = (m << 2) + q;
    int e1 = e0 + 4;
    const double* w0 = s0 + e0 * S0STR;
    const double* w1r = s0 + e1 * S0STR;
    double a0 = sb0[e0], a1 = sb0[e1];
#pragma unroll
    for (int k = 0; k < C3_; k++) {
      a0 = fma(pv[k], w0[k], a0);
      a1 = fma(pv[k], w1r[k], a1);
    }
    a0 = a0 > 0.0 ? a0 : 0.0;   // relu-as-multiply: 0-adds are exact
    a1 = a1 > 0.0 ? a1 : 0.0;
    const double* v0 = fc1d + (e0 << 4);
    const double* v1 = fc1d + (e1 << 4);
#pragma unroll
    for (int c = 0; c < C_; c++) {
      dx[c] = fma(a0, v0[c], dx[c]);
      dx[c] = fma(a1, v1[c], dx[c]);
    }
  }
  // quad butterfly reduce (commutative adds -> identical bits in all lanes)
#pragma unroll
  for (int c = 0; c < C_; c++) {
    dx[c] += __shfl_xor(dx[c], 1);
    dx[c] += __shfl_xor(dx[c], 2);
  }
  // static-index select of this lane's 4 channels (avoid runtime reg indexing)
  double d0 = (q & 2) ? ((q & 1) ? dx[12] : dx[8])  : ((q & 1) ? dx[4] : dx[0]);
  double d1 = (q & 2) ? ((q & 1) ? dx[13] : dx[9])  : ((q & 1) ? dx[5] : dx[1]);
  double d2 = (q & 2) ? ((q & 1) ? dx[14] : dx[10]) : ((q & 1) ? dx[6] : dx[2]);
  double d3 = (q & 2) ? ((q & 1) ? dx[15] : dx[11]) : ((q & 1) ? dx[7] : dx[3]);
  const double* xc = x + ((size_t)cell << 4) + (q << 2);
  double* xo = xn + ((size_t)cell << 4) + (q << 2);
  xo[0] = xc[0] + d0 * upd;
  xo[1] = xc[1] + d1 * upd;
  xo[2] = xc[2] + d2 * upd;
  xo[3] = xc[3] + d3 * upd;
}

// ---------------------------------------------------------------------------
// life mask: x_new = xn * (alive(x_old) & alive(xn)); emit x_steps[n]
// thread = (cell, c)  -- alpha loads broadcast across the 16 c-lanes
// ---------------------------------------------------------------------------
__global__ void k_life(const double* __restrict__ xold, const double* __restrict__ xn,
                       double* __restrict__ xout, float* __restrict__ out_x, int n) {
  int idx = blockIdx.x * 256 + threadIdx.x;
  int c = idx & 15;
  int cell = idx >> 4;
  int j = cell % W_; int t = cell / W_; int i = t % H_; int b = t / H_;
  double mo = -1e300, mn2 = -1e300;
  for (int di = -1; di <= 1; di++) {
    int ii = i + di; if (ii < 0 || ii >= H_) continue;
    for (int dj = -1; dj <= 1; dj++) {
      int jj = j + dj; if (jj < 0 || jj >= W_) continue;
      size_t nb = (size_t)((b * H_ + ii) * W_ + jj) * C_;
      double a0 = xold[nb + 3]; if (a0 > mo) mo = a0;
      double a1 = xn[nb + 3];   if (a1 > mn2) mn2 = a1;
    }
  }
  bool life = (mo > 0.1) && (mn2 > 0.1);
  double v = life ? xn[((size_t)cell << 4) + c] : 0.0;
  xout[((size_t)cell << 4) + c] = v;
  out_x[(size_t)n * NCELL * C_ + ((size_t)cell << 4) + c] = (float)v;
}

// ---------------------------------------------------------------------------
// final emission for scan step 64
// ---------------------------------------------------------------------------
__global__ void k_emit(const double* __restrict__ lam, const double* __restrict__ un,
                       float* __restrict__ out_lam, double* __restrict__ p_buf) {
  int cell = blockIdx.x * 256 + threadIdx.x;
  double l = lam[cell];
  size_t o = (size_t)(T_ - 1) * NCELL + cell;
  out_lam[o] = (float)l;
  p_buf[o] = un[cell] * l + 1e-6;
}

// ---------------------------------------------------------------------------
// final: p_norm[t] = p[t] / sum_t p[t]
// ---------------------------------------------------------------------------
__global__ void k_pnorm(const double* __restrict__ p_buf, float* __restrict__ out_p) {
  int cell = blockIdx.x * 256 + threadIdx.x;
  double s = 0.0;
  for (int t = 0; t < T_; t++) s += p_buf[(size_t)t * NCELL + cell];
  for (int t = 0; t < T_; t++)
    out_p[(size_t)t * NCELL + cell] = (float)(p_buf[(size_t)t * NCELL + cell] / s);
}

// ---------------------------------------------------------------------------
extern "C" void kernel_launch(void* const* d_in, const int* in_sizes, int n_in,
                              void* d_out, int out_size, void* d_ws, size_t ws_size,
                              hipStream_t stream) {
  const float* xin = (const float*)d_in[0];
  const float* w1  = (const float*)d_in[1];
  const float* b1  = (const float*)d_in[2];
  const float* w2  = (const float*)d_in[3];
  const float* b2  = (const float*)d_in[4];
  const float* f0w = (const float*)d_in[5];
  const float* f0b = (const float*)d_in[6];
  const float* f1w = (const float*)d_in[7];

  float* out     = (float*)d_out;
  float* out_x   = out;                                   // (64, NCELL, 16)
  float* out_p   = out_x + (size_t)T_ * NCELL * C_;       // (64, NCELL)
  float* out_lam = out_p + (size_t)T_ * NCELL;            // (64, NCELL)
  float* out_upd = out_lam + (size_t)T_ * NCELL;          // (64, NCELL)

  // workspace layout (all f64)
  double* ws    = (double*)d_ws;
  double* xA    = ws;                                  // NCELL*16
  double* xB    = xA + (size_t)NCELL * C_;             // NCELL*16
  double* xn    = xB + (size_t)NCELL * C_;             // NCELL*16
  double* hbuf  = xn + (size_t)NCELL * C_;             // NCELL*16
  double* lamA  = hbuf + (size_t)NCELL * HP_;          // NCELL
  double* lamB  = lamA + NCELL;                        // NCELL
  double* un    = lamB + NCELL;                        // NCELL
  double* p_buf = un + NCELL;                          // 64*NCELL
  double* weffd = p_buf + (size_t)T_ * NCELL;          // 6400
  double* fc0t  = weffd + 6400;                        // 128*49
  double* fc1d  = fc0t + HE_ * S0STR;                  // 2048
  double* w2d   = fc1d + HE_ * C_;                     // 144
  double* f0bd  = w2d + 144;                           // 128
  double* b1d   = f0bd + HE_;                          // 16

  k_init<<<2592, 256, 0, stream>>>(xin, xA, un);
  k_prep<<<26, 256, 0, stream>>>(w1, b1, f0w, f0b, f1w, w2,
                                 weffd, b1d, fc0t, fc1d, w2d, f0bd);

  double* cur = lamA;   // lagged lam entering iteration n
  double* nxt = lamB;

  for (int n = 0; n <= T_ - 1; n++) {
    k_conv1f<<<IBLK + EBLK, 256, 0, stream>>>(xA, weffd, b1d, w1, hbuf);
    uint32_t kx0 = 0u, kx1 = (uint32_t)n;
    threefry2x32(0u, 42u, kx0, kx1);
    // n==0: fresh lambda is both written to cur and used for the bernoulli
    k_upd<<<IBLK, 256, 0, stream>>>(xA, hbuf, cur, fc0t, fc1d, w2d, f0bd, b2,
                                    (n == 0 ? cur : nxt), xn, out_upd, un,
                                    out_lam, p_buf, kx0, kx1, n);
    k_life<<<2592, 256, 0, stream>>>(xA, xn, xB, out_x, n);
    { double* t = xA; xA = xB; xB = t; }
    if (n >= 1) { double* t = cur; cur = nxt; nxt = t; }
  }

  // scan step 64: emit lam_steps[63], p_steps[63] from cur = L(perc(x62))
  k_emit<<<162, 256, 0, stream>>>(cur, un, out_lam, p_buf);
  k_pnorm<<<162, 256, 0, stream>>>(p_buf, out_p);
}

// Round 3
// 14779.918 us; speedup vs baseline: 1.0012x; 1.0012x over previous
//
#include <hip/hip_runtime.h>
#include <cstdint>
#include <cmath>

// Problem constants
#define B_    8
#define H_    72
#define W_    72
#define C_    16
#define C3_   48
#define HP_   16
#define HE_   128
#define T_    64
#define NCELL 41472      // B*H*W
#define NEDGE 2272       // (2*72 + 2*70) * 8 boundary cells

// ---------------------------------------------------------------------------
// JAX threefry2x32 (20 rounds)
// ---------------------------------------------------------------------------
__host__ __device__ __forceinline__ void threefry2x32(uint32_t k0, uint32_t k1,
                                                      uint32_t& x0, uint32_t& x1) {
  uint32_t ks2 = k0 ^ k1 ^ 0x1BD11BDAu;
  x0 += k0; x1 += k1;
#define TF_R(r) { x0 += x1; x1 = (x1 << (r)) | (x1 >> (32 - (r))); x1 ^= x0; }
  TF_R(13) TF_R(15) TF_R(26) TF_R(6)
  x0 += k1; x1 += ks2 + 1u;
  TF_R(17) TF_R(29) TF_R(16) TF_R(24)
  x0 += ks2; x1 += k0 + 2u;
  TF_R(13) TF_R(15) TF_R(26) TF_R(6)
  x0 += k0; x1 += k1 + 3u;
  TF_R(17) TF_R(29) TF_R(16) TF_R(24)
  x0 += k1; x1 += ks2 + 4u;
  TF_R(13) TF_R(15) TF_R(26) TF_R(6)
  x0 += ks2; x1 += k0 + 5u;
#undef TF_R
}

// ---------------------------------------------------------------------------
// init: f32 input -> f64 state; un = 1
// ---------------------------------------------------------------------------
__global__ void k_init(const float* __restrict__ xin, double* __restrict__ xA,
                       double* __restrict__ un) {
  int idx = blockIdx.x * 256 + threadIdx.x;
  if (idx < NCELL * C_) xA[idx] = (double)xin[idx];
  if (idx < NCELL) un[idx] = 1.0;
}

// ---------------------------------------------------------------------------
// prep (once): effective 5x5 conv1 weights (conv1 o perceive, exact f64
// combination), f64 copies of fc0 (transposed [e][k]), fc1, w2, w1, biases.
// ---------------------------------------------------------------------------
__global__ void k_prep(const float* __restrict__ w1, const float* __restrict__ b1,
                       const float* __restrict__ f0w, const float* __restrict__ f0b,
                       const float* __restrict__ f1w, const float* __restrict__ w2,
                       double* __restrict__ weffd, double* __restrict__ b1d,
                       double* __restrict__ fc0t, double* __restrict__ fc1d,
                       double* __restrict__ w2d, double* __restrict__ f0bd,
                       double* __restrict__ w1d) {
  int gid = blockIdx.x * 256 + threadIdx.x;
  const int stride = 26 * 256;
  // w_eff[u][v][ic][oc]
  for (int t = gid; t < 6400; t += stride) {
    int oc = t & 15;
    int c  = (t >> 4) & 15;
    int pos = t >> 8;             // 0..24
    int u = pos / 5, v = pos % 5;
    double acc = 0.0;
    for (int ei = 0; ei < 3; ei++) {
      int di = u - ei; if (di < 0 || di > 2) continue;
      for (int ej = 0; ej < 3; ej++) {
        int dj = v - ej; if (dj < 0 || dj > 2) continue;
        const float* wb = w1 + (size_t)((ei * 3 + ej) * C3_) * HP_ + oc;
        if (di == 1 && dj == 1) acc += (double)wb[c * HP_];
        double rf1 = (di == 0) ? -0.125 : (di == 2) ? 0.125 : 0.0;
        if (rf1 != 0.0) {
          double cf1 = (dj == 1) ? 2.0 : 1.0;
          acc += (double)wb[(C_ + c) * HP_] * (rf1 * cf1);
        }
        double cf2 = (dj == 0) ? -0.125 : (dj == 2) ? 0.125 : 0.0;
        if (cf2 != 0.0) {
          double rf2 = (di == 1) ? 2.0 : 1.0;
          acc += (double)wb[(2 * C_ + c) * HP_] * (cf2 * rf2);
        }
      }
    }
    weffd[t] = acc;
  }
  // fc0 transposed: fc0t[e*48 + k] = f0w[k*128 + e]
  for (int t = gid; t < C3_ * HE_; t += stride) {
    int k = t >> 7, e = t & 127;
    fc0t[e * C3_ + k] = (double)f0w[t];
  }
  for (int t = gid; t < HE_ * C_; t += stride) fc1d[t] = (double)f1w[t];
  for (int t = gid; t < 144; t += stride) w2d[t] = (double)w2[t];
  for (int t = gid; t < HE_; t += stride) f0bd[t] = (double)f0b[t];
  for (int t = gid; t < HP_; t += stride) b1d[t] = (double)b1[t];
  for (int t = gid; t < 3 * 3 * C3_ * HP_; t += stride) w1d[t] = (double)w1[t];
}

// ---------------------------------------------------------------------------
// conv1 fused with perceive. lane = cell; weights via wave-uniform scalar
// loads (no LDS). Interior: direct 5x5 w_eff, wave-uniform oc-half.
// Boundary ring: tail waves, one wave-uniform oc each, exact two-stage math.
// Grid: 324 interior blocks + 144 tail blocks, 256 threads.
// ---------------------------------------------------------------------------
__global__ void __launch_bounds__(256) k_conv1(const double* __restrict__ x,
    const double* __restrict__ weffd, const double* __restrict__ b1d,
    const double* __restrict__ w1d, double* __restrict__ hbuf) {
  int lane = threadIdx.x & 63;
  int wv = __builtin_amdgcn_readfirstlane(threadIdx.x >> 6);
  if (blockIdx.x < 324) {
    int gw = blockIdx.x * 4 + wv;        // 0..1295
    int cellw = gw >> 1;                 // 0..647
    int ocb = (gw & 1) << 3;             // wave-uniform oc base (0 or 8)
    int cell = (cellw << 6) + lane;
    int j = cell % W_; int t2 = cell / W_; int i = t2 % H_; int b = t2 / H_;
    if (i == 0 || i == H_ - 1 || j == 0 || j == W_ - 1) return;  // ring: tail owns
    double acc[8];
#pragma unroll
    for (int o = 0; o < 8; o++) acc[o] = b1d[ocb + o];
#pragma unroll 1
    for (int u = 0; u < 5; u++) {
      int ii = i + u - 2; if (ii < 0 || ii >= H_) continue;
#pragma unroll 1
      for (int v = 0; v < 5; v++) {
        int jj = j + v - 2; if (jj < 0 || jj >= W_) continue;
        const double* xp = x + ((size_t)((b * H_ + ii) * W_ + jj) << 4);
        const double* wp = weffd + (u * 5 + v) * 256 + ocb;   // uniform
        double xv[16];
#pragma unroll
        for (int ic = 0; ic < 16; ic++) xv[ic] = xp[ic];
#pragma unroll
        for (int ic = 0; ic < 16; ic++) {
#pragma unroll
          for (int o = 0; o < 8; o++)
            acc[o] = fma(xv[ic], wp[ic * 16 + o], acc[o]);
        }
      }
    }
    double* hp = hbuf + ((size_t)cell << 4) + ocb;
#pragma unroll
    for (int o = 0; o < 8; o++) hp[o] = acc[o] > 0.0 ? acc[o] : 0.0;
  } else {
    // ---- boundary ring: exact two-stage; one oc per wave (uniform) ----
    int gw = (blockIdx.x - 324) * 4 + wv;   // 0..575
    int oc = gw & 15;                       // wave-uniform
    int grp = gw >> 4;                      // 0..35
    int ecell = (grp << 6) + lane;
    if (ecell >= NEDGE) return;
    int b = ecell / 284, r = ecell % 284;
    int i, j;
    if (r < 72)       { i = 0;       j = r; }
    else if (r < 144) { i = H_ - 1;  j = r - 72; }
    else if (r < 214) { i = r - 143; j = 0; }
    else              { i = r - 213; j = W_ - 1; }
    int cell = (b * H_ + i) * W_ + j;
    double acc = b1d[oc];
    for (int ei = 0; ei < 3; ei++) {
      int pi = i + ei - 1; if (pi < 0 || pi >= H_) continue;
      for (int ej = 0; ej < 3; ej++) {
        int pj = j + ej - 1; if (pj < 0 || pj >= W_) continue;
        const double* wb = w1d + (size_t)((ei * 3 + ej) * C3_) * HP_ + oc;
        for (int c = 0; c < C_; c++) {
          double v[3][3];
#pragma unroll
          for (int a2 = 0; a2 < 3; a2++) {
#pragma unroll
            for (int b2i = 0; b2i < 3; b2i++) {
              int ii2 = pi + a2 - 1, jj2 = pj + b2i - 1;
              bool ok = (ii2 >= 0 && ii2 < H_ && jj2 >= 0 && jj2 < W_);
              v[a2][b2i] = ok ? x[(((size_t)((b * H_ + ii2) * W_ + jj2)) << 4) + c] : 0.0;
            }
          }
          double ctr = v[1][1];
          double dw1 = (-v[0][0] - 2.0 * v[0][1] - v[0][2] + v[2][0] + 2.0 * v[2][1] + v[2][2]) * 0.125;
          double dw2 = (-v[0][0] + v[0][2] - 2.0 * v[1][0] + 2.0 * v[1][2] - v[2][0] + v[2][2]) * 0.125;
          acc += ctr * wb[c * HP_] + dw1 * wb[(C_ + c) * HP_] + dw2 * wb[(2 * C_ + c) * HP_];
        }
      }
    }
    hbuf[((size_t)cell << 4) + oc] = acc > 0.0 ? acc : 0.0;
  }
}

// ---------------------------------------------------------------------------
// fused conv2 + update. lane = cell; 2 waves per 64-cell block split the
// 128 hidden units (e-base wave-uniform -> scalar weight loads).
// Wave 1 writes its partial dx to LDS; wave 0 combines, does conv2/lambda/
// RNG/bookkeeping and writes xn.
// ---------------------------------------------------------------------------
__global__ void __launch_bounds__(128) k_upd(
    const double* __restrict__ x, const double* __restrict__ hbuf,
    const double* __restrict__ lamPrev, const double* __restrict__ fc0t,
    const double* __restrict__ fc1d, const double* __restrict__ w2d,
    const double* __restrict__ f0bd, const float* __restrict__ b2,
    double* __restrict__ lamNext, double* __restrict__ xn,
    float* __restrict__ out_upd, double* __restrict__ un,
    float* __restrict__ out_lam, double* __restrict__ p_buf,
    uint32_t k0, uint32_t k1, int n) {
  __shared__ double sdx[64][17];   // stride 17: conflict-free
  int lane = threadIdx.x & 63;
  int wv = __builtin_amdgcn_readfirstlane(threadIdx.x >> 6);  // 0 or 1
  int cell = (blockIdx.x << 6) + lane;
  int j = cell % W_; int t2 = cell / W_; int i = t2 % H_; int b = t2 / H_;

  // ---- perceive on the fly (both waves; bit-identical formulas) ----
  double pv[C3_];
#pragma unroll
  for (int k = 0; k < C3_; k++) pv[k] = 0.0;
#pragma unroll
  for (int p = 0; p < 9; p++) {
    const int di = p / 3, dj = p % 3;
    const double k1c = (di == 0 ? -0.125 : di == 2 ? 0.125 : 0.0) * (dj == 1 ? 2.0 : 1.0);
    const double k2c = (dj == 0 ? -0.125 : dj == 2 ? 0.125 : 0.0) * (di == 1 ? 2.0 : 1.0);
    int ii = i + di - 1, jj = j + dj - 1;
    if (ii < 0 || ii >= H_ || jj < 0 || jj >= W_) continue;
    const double* xp = x + ((size_t)((b * H_ + ii) * W_ + jj) << 4);
#pragma unroll
    for (int c = 0; c < C_; c++) {
      double xv = xp[c];
      if (p == 4) pv[c] += xv;
      if (k1c != 0.0) pv[C_ + c] = fma(k1c, xv, pv[C_ + c]);
      if (k2c != 0.0) pv[2 * C_ + c] = fma(k2c, xv, pv[2 * C_ + c]);
    }
  }

  // ---- MLP layer1+2 for this wave's 64-e half; scalar weights ----
  double dx[C_];
#pragma unroll
  for (int c = 0; c < C_; c++) dx[c] = 0.0;
  int ebase = wv << 6;   // uniform
#pragma unroll 2
  for (int eg = 0; eg < 64; eg += 4) {
    const double* wrow = fc0t + (size_t)(ebase + eg) * C3_;   // uniform
    double a0 = f0bd[ebase + eg + 0];
    double a1 = f0bd[ebase + eg + 1];
    double a2 = f0bd[ebase + eg + 2];
    double a3 = f0bd[ebase + eg + 3];
#pragma unroll
    for (int k = 0; k < C3_; k++) {
      a0 = fma(pv[k], wrow[k], a0);
      a1 = fma(pv[k], wrow[C3_ + k], a1);
      a2 = fma(pv[k], wrow[2 * C3_ + k], a2);
      a3 = fma(pv[k], wrow[3 * C3_ + k], a3);
    }
    a0 = a0 > 0.0 ? a0 : 0.0;
    a1 = a1 > 0.0 ? a1 : 0.0;
    a2 = a2 > 0.0 ? a2 : 0.0;
    a3 = a3 > 0.0 ? a3 : 0.0;
    const double* v0 = fc1d + ((size_t)(ebase + eg) << 4);    // uniform
#pragma unroll
    for (int c = 0; c < C_; c++) {
      double s = fma(a0, v0[c], dx[c]);
      s = fma(a1, v0[16 + c], s);
      s = fma(a2, v0[32 + c], s);
      s = fma(a3, v0[48 + c], s);
      dx[c] = s;
    }
  }

  if (wv == 1) {
#pragma unroll
    for (int c = 0; c < C_; c++) sdx[lane][c] = dx[c];
  }
  __syncthreads();
  if (wv == 1) return;

#pragma unroll
  for (int c = 0; c < C_; c++) dx[c] += sdx[lane][c];

  // ---- conv2 -> fresh lambda (wave 0 only) ----
  double z = (double)b2[0];
  for (int di = 0; di < 3; di++) {
    int ii = i + di - 1; if (ii < 0 || ii >= H_) continue;
    for (int dj = 0; dj < 3; dj++) {
      int jj = j + dj - 1; if (jj < 0 || jj >= W_) continue;
      const double* hh = hbuf + ((size_t)((b * H_ + ii) * W_ + jj) << 4);
      const double* ww = w2d + (di * 3 + dj) * HP_;   // uniform
#pragma unroll
      for (int ic = 0; ic < HP_; ic++) z = fma(hh[ic], ww[ic], z);
    }
  }
  double lamF = 1.0 / (1.0 + exp(-z));
  lamNext[cell] = lamF;
  double l = (n == 0) ? lamF : lamPrev[cell];

  // ---- scan bookkeeping with lagged lam ----
  if (n >= 1) {
    size_t o = (size_t)(n - 1) * NCELL + cell;
    out_lam[o] = (float)l;
    double u = un[cell];
    p_buf[o] = u * l + 1e-6;
    un[cell] = u * (1.0 - l);
  }

  // ---- RNG + state write ----
  uint32_t r0 = 0u, r1 = (uint32_t)cell;
  threefry2x32(k0, k1, r0, r1);
  double uf = (double)(r0 ^ r1) * 0x1p-32;
  double upd = (uf < l) ? 0.0 : 1.0;
  out_upd[(size_t)n * NCELL + cell] = (float)upd;
  const double* xc = x + ((size_t)cell << 4);
  double* xo = xn + ((size_t)cell << 4);
#pragma unroll
  for (int c = 0; c < C_; c++) xo[c] = xc[c] + dx[c] * upd;
}

// ---------------------------------------------------------------------------
// life mask: x_new = xn * (alive(x_old) & alive(xn)); emit x_steps[n]
// thread = (cell, c)
// ---------------------------------------------------------------------------
__global__ void k_life(const double* __restrict__ xold, const double* __restrict__ xn,
                       double* __restrict__ xout, float* __restrict__ out_x, int n) {
  int idx = blockIdx.x * 256 + threadIdx.x;
  int c = idx & 15;
  int cell = idx >> 4;
  int j = cell % W_; int t = cell / W_; int i = t % H_; int b = t / H_;
  double mo = -1e300, mn2 = -1e300;
  for (int di = -1; di <= 1; di++) {
    int ii = i + di; if (ii < 0 || ii >= H_) continue;
    for (int dj = -1; dj <= 1; dj++) {
      int jj = j + dj; if (jj < 0 || jj >= W_) continue;
      size_t nb = (size_t)((b * H_ + ii) * W_ + jj) * C_;
      double a0 = xold[nb + 3]; if (a0 > mo) mo = a0;
      double a1 = xn[nb + 3];   if (a1 > mn2) mn2 = a1;
    }
  }
  bool life = (mo > 0.1) && (mn2 > 0.1);
  double v = life ? xn[((size_t)cell << 4) + c] : 0.0;
  xout[((size_t)cell << 4) + c] = v;
  out_x[(size_t)n * NCELL * C_ + ((size_t)cell << 4) + c] = (float)v;
}

// ---------------------------------------------------------------------------
// final emission for scan step 64
// ---------------------------------------------------------------------------
__global__ void k_emit(const double* __restrict__ lam, const double* __restrict__ un,
                       float* __restrict__ out_lam, double* __restrict__ p_buf) {
  int cell = blockIdx.x * 256 + threadIdx.x;
  double l = lam[cell];
  size_t o = (size_t)(T_ - 1) * NCELL + cell;
  out_lam[o] = (float)l;
  p_buf[o] = un[cell] * l + 1e-6;
}

// ---------------------------------------------------------------------------
// final: p_norm[t] = p[t] / sum_t p[t]
// ---------------------------------------------------------------------------
__global__ void k_pnorm(const double* __restrict__ p_buf, float* __restrict__ out_p) {
  int cell = blockIdx.x * 256 + threadIdx.x;
  double s = 0.0;
  for (int t = 0; t < T_; t++) s += p_buf[(size_t)t * NCELL + cell];
  for (int t = 0; t < T_; t++)
    out_p[(size_t)t * NCELL + cell] = (float)(p_buf[(size_t)t * NCELL + cell] / s);
}

// ---------------------------------------------------------------------------
extern "C" void kernel_launch(void* const* d_in, const int* in_sizes, int n_in,
                              void* d_out, int out_size, void* d_ws, size_t ws_size,
                              hipStream_t stream) {
  const float* xin = (const float*)d_in[0];
  const float* w1  = (const float*)d_in[1];
  const float* b1  = (const float*)d_in[2];
  const float* w2  = (const float*)d_in[3];
  const float* b2  = (const float*)d_in[4];
  const float* f0w = (const float*)d_in[5];
  const float* f0b = (const float*)d_in[6];
  const float* f1w = (const float*)d_in[7];

  float* out     = (float*)d_out;
  float* out_x   = out;                                   // (64, NCELL, 16)
  float* out_p   = out_x + (size_t)T_ * NCELL * C_;       // (64, NCELL)
  float* out_lam = out_p + (size_t)T_ * NCELL;            // (64, NCELL)
  float* out_upd = out_lam + (size_t)T_ * NCELL;          // (64, NCELL)

  // workspace layout (all f64)
  double* ws    = (double*)d_ws;
  double* xA    = ws;                                  // NCELL*16
  double* xB    = xA + (size_t)NCELL * C_;             // NCELL*16
  double* xn    = xB + (size_t)NCELL * C_;             // NCELL*16
  double* hbuf  = xn + (size_t)NCELL * C_;             // NCELL*16
  double* lamA  = hbuf + (size_t)NCELL * HP_;          // NCELL
  double* lamB  = lamA + NCELL;                        // NCELL
  double* un    = lamB + NCELL;                        // NCELL
  double* p_buf = un + NCELL;                          // 64*NCELL
  double* weffd = p_buf + (size_t)T_ * NCELL;          // 6400
  double* fc0t  = weffd + 6400;                        // 128*48
  double* fc1d  = fc0t + HE_ * C3_;                    // 2048
  double* w2d   = fc1d + HE_ * C_;                     // 144
  double* f0bd  = w2d + 144;                           // 128
  double* b1d   = f0bd + HE_;                          // 16
  double* w1d   = b1d + HP_;                           // 6912

  k_init<<<2592, 256, 0, stream>>>(xin, xA, un);
  k_prep<<<26, 256, 0, stream>>>(w1, b1, f0w, f0b, f1w, w2,
                                 weffd, b1d, fc0t, fc1d, w2d, f0bd, w1d);

  double* cur = lamA;   // lagged lam entering iteration n
  double* nxt = lamB;

  for (int n = 0; n <= T_ - 1; n++) {
    k_conv1<<<468, 256, 0, stream>>>(xA, weffd, b1d, w1d, hbuf);
    uint32_t kx0 = 0u, kx1 = (uint32_t)n;
    threefry2x32(0u, 42u, kx0, kx1);
    k_upd<<<648, 128, 0, stream>>>(xA, hbuf, cur, fc0t, fc1d, w2d, f0bd, b2,
                                   (n == 0 ? cur : nxt), xn, out_upd, un,
                                   out_lam, p_buf, kx0, kx1, n);
    k_life<<<2592, 256, 0, stream>>>(xA, xn, xB, out_x, n);
    { double* t = xA; xA = xB; xB = t; }
    if (n >= 1) { double* t = cur; cur = nxt; nxt = t; }
  }

  // scan step 64: emit lam_steps[63], p_steps[63] from cur = L(perc(x62))
  k_emit<<<162, 256, 0, stream>>>(cur, un, out_lam, p_buf);
  k_pnorm<<<162, 256, 0, stream>>>(p_buf, out_p);
}